// Round 3
// baseline (3714.188 us; speedup 1.0000x reference)
//
#include <hip/hip_runtime.h>

#define BN 4096     // batch
#define DF 784
#define HALFF 392
#define HIDF 512
#define NBLK 20
#define KS1 448     // padded K for GEMM1 (392 -> 7*64)
#define KS2 512     // K for GEMM2 (8*64)

typedef _Float16 f16;
typedef _Float16 half4v __attribute__((ext_vector_type(4)));
typedef _Float16 half8v __attribute__((ext_vector_type(8)));
typedef float    fx4    __attribute__((ext_vector_type(4)));

// ---------------------------------------------------------------------------
// prep_k: convert fp32 weights [m][k][N] (k-major) -> fp16 [m][n][KS] (n-major),
// zero-padding k in [K, KS). Classic 32x32 LDS transpose.
// grid ((KS/32) * ceil(N/32), M), block (32, 8).
// ---------------------------------------------------------------------------
__global__ void prep_k(const float* __restrict__ src, f16* __restrict__ dst,
                       int K, int N, int KS, long srcMat, long dstMat)
{
    __shared__ float tile[32][33];
    const int m = blockIdx.y;
    const int ktiles = KS >> 5;
    const int kt = blockIdx.x % ktiles, nt = blockIdx.x / ktiles;
    const int tx = threadIdx.x, ty = threadIdx.y;
    const float* s = src + (long)m * srcMat;
    f16* d = dst + (long)m * dstMat;
    #pragma unroll
    for (int j = 0; j < 4; j++) {
        int k = kt * 32 + ty + j * 8, n = nt * 32 + tx;
        tile[ty + j * 8][tx] = (k < K && n < N) ? s[(long)k * N + n] : 0.f;
    }
    __syncthreads();
    #pragma unroll
    for (int j = 0; j < 4; j++) {
        int n = nt * 32 + ty + j * 8, k = kt * 32 + tx;
        if (n < N) d[(long)n * KS + k] = (f16)tile[tx][ty + j * 8];
    }
}

// ---------------------------------------------------------------------------
// GEMM1: Hb[b][n] = relu( sum_{k<392} Wf[n][k]*A[k][b] + Wcond[l[b]][n] + bias[n] )
// A[k][b] = Vsrc[rowmap ? rowmap[k] : k][b]  (fp32 -> fp16 on staging)
// Wf: fp16 [512][KS1] (k-padded with zeros). Hb: fp16 [4096][512].
// A-fragments direct from global; B staged in chunk-XOR-swizzled LDS.
// grid (8, 32), block 256.
// ---------------------------------------------------------------------------
__global__ __launch_bounds__(256)
void gemm1_k(const float* __restrict__ Vsrc, const int* __restrict__ rowmap,
             const f16* __restrict__ Wf, const float* __restrict__ Wcond,
             const float* __restrict__ bias, const int* __restrict__ lvec,
             f16* __restrict__ Hb)
{
    __shared__ __align__(16) f16 Al[128 * 64];   // [b][chunk^(b&7)][8]

    const int tid  = threadIdx.x;
    const int n0   = blockIdx.x * 64;
    const int b0   = blockIdx.y * 128;
    const int wid  = tid >> 6, lane = tid & 63;
    const int wn   = wid >> 1, wb = wid & 1;
    const int ln16 = lane & 15, koct = lane >> 4;

    const int br = tid & 127;        // LDS row (b) this thread stages
    const int cb = (tid >> 7) * 4;   // chunk base (0 or 4) — wave-uniform

    fx4 acc[2][4];
    #pragma unroll
    for (int i = 0; i < 2; i++)
        #pragma unroll
        for (int j = 0; j < 4; j++) acc[i][j] = (fx4)0.f;

    for (int k0 = 0; k0 < HALFF; k0 += 64) {
        __syncthreads();
        // ---- stage A tile: 128b x 64k fp16, transposed, swizzled
        #pragma unroll
        for (int ch = 0; ch < 4; ch++) {
            int c  = cb + ch;
            int kb = k0 + c * 8;
            half8v h;
            if (kb + 8 <= HALFF) {   // 392 = 49*8: chunks fully valid or fully pad
                #pragma unroll
                for (int kk = 0; kk < 8; kk++) {
                    int k = kb + kk;
                    int r = rowmap ? rowmap[k] : k;
                    h[kk] = (f16)Vsrc[(long)r * BN + b0 + br];
                }
            } else {
                #pragma unroll
                for (int kk = 0; kk < 8; kk++) h[kk] = (f16)0.f;
            }
            *(half8v*)&Al[br * 64 + ((c ^ (br & 7)) * 8)] = h;
        }
        __syncthreads();
        // ---- fragments + MFMA (2 k-slices of 32)
        #pragma unroll
        for (int ks = 0; ks < 2; ks++) {
            half8v af[2], bf[4];
            #pragma unroll
            for (int ni = 0; ni < 2; ni++) {
                int n = n0 + wn * 32 + ni * 16 + ln16;
                af[ni] = *(const half8v*)&Wf[(long)n * KS1 + k0 + ks * 32 + koct * 8];
            }
            #pragma unroll
            for (int bi = 0; bi < 4; bi++) {
                int b = wb * 64 + bi * 16 + ln16;
                int c = (ks * 4 + koct) ^ (b & 7);
                bf[bi] = *(const half8v*)&Al[b * 64 + c * 8];
            }
            #pragma unroll
            for (int ni = 0; ni < 2; ni++)
                #pragma unroll
                for (int bi = 0; bi < 4; bi++)
                    acc[ni][bi] = __builtin_amdgcn_mfma_f32_16x16x32_f16(af[ni], bf[bi], acc[ni][bi], 0, 0, 0);
        }
    }

    // ---- epilogue: + bias + cond row, relu, store Hb[b][n] (half4 per quad)
    #pragma unroll
    for (int bi = 0; bi < 4; bi++) {
        int b = b0 + wb * 64 + bi * 16 + ln16;
        int lvb = lvec[b];
        const float* crow = Wcond + (long)lvb * HIDF;
        #pragma unroll
        for (int ni = 0; ni < 2; ni++) {
            int nb = n0 + wn * 32 + ni * 16 + koct * 4;
            half4v o;
            #pragma unroll
            for (int r = 0; r < 4; r++) {
                float v = acc[ni][bi][r] + bias[nb + r] + crow[nb + r];
                o[r] = (f16)fmaxf(v, 0.f);
            }
            *(half4v*)&Hb[(long)b * HIDF + nb] = o;
        }
    }
}

// ---------------------------------------------------------------------------
// Fused GEMM2 + coupling.
//   s[d][b] = sum_k Wf[d][k]      * H[k][b] + bias[d]
//   t[d][b] = sum_k Wf[d+392][k]  * H[k][b] + bias[d+392]
//   ls = 0.636*atan(s); Vdst[d][b] = exp(ls)*Vcur[permRow[d]][b] + t; jac[b]+=ls
// Hb: fp16 [4096][512] (b-major!) -> B staging is a pure swizzled fp16 copy.
// Wf: fp16 [784][512]. fragment ni=0 -> s rows, ni=1 -> t rows.
// grid (13, 32), block 256.
// ---------------------------------------------------------------------------
__global__ __launch_bounds__(256)
void gemm2c_k(const f16* __restrict__ Hb, const f16* __restrict__ Wf,
              const float* __restrict__ bias, const float* __restrict__ Vcur,
              const int* __restrict__ permRow, float* __restrict__ Vdst,
              float* __restrict__ jac)
{
    __shared__ __align__(16) f16 Bl[128 * 64];

    const int tid  = threadIdx.x;
    const int d0   = blockIdx.x * 32;
    const int b0   = blockIdx.y * 128;
    const int wid  = tid >> 6, lane = tid & 63;
    const int wn   = wid >> 1, wb = wid & 1;
    const int ln16 = lane & 15, koct = lane >> 4;

    const int br = tid & 127;
    const int cb = (tid >> 7) * 4;

    fx4 acc[2][4];
    #pragma unroll
    for (int i = 0; i < 2; i++)
        #pragma unroll
        for (int j = 0; j < 4; j++) acc[i][j] = (fx4)0.f;

    // A-fragment rows (clamped for the d0=384 tail block; epilogue guards)
    const int dr  = d0 + wn * 16 + ln16;
    const int drc = (dr < HALFF) ? dr : (HALFF - 1);

    for (int k0 = 0; k0 < HIDF; k0 += 64) {
        __syncthreads();
        // ---- stage B tile: pure fp16 copy from Hb[b][k], swizzled
        #pragma unroll
        for (int ch = 0; ch < 4; ch++) {
            int c = cb + ch;
            half8v h = *(const half8v*)&Hb[(long)(b0 + br) * HIDF + k0 + c * 8];
            *(half8v*)&Bl[br * 64 + ((c ^ (br & 7)) * 8)] = h;
        }
        __syncthreads();
        #pragma unroll
        for (int ks = 0; ks < 2; ks++) {
            half8v af[2], bf[4];
            af[0] = *(const half8v*)&Wf[(long)drc * KS2 + k0 + ks * 32 + koct * 8];
            af[1] = *(const half8v*)&Wf[(long)(drc + HALFF) * KS2 + k0 + ks * 32 + koct * 8];
            #pragma unroll
            for (int bi = 0; bi < 4; bi++) {
                int b = wb * 64 + bi * 16 + ln16;
                int c = (ks * 4 + koct) ^ (b & 7);
                bf[bi] = *(const half8v*)&Bl[b * 64 + c * 8];
            }
            #pragma unroll
            for (int ni = 0; ni < 2; ni++)
                #pragma unroll
                for (int bi = 0; bi < 4; bi++)
                    acc[ni][bi] = __builtin_amdgcn_mfma_f32_16x16x32_f16(af[ni], bf[bi], acc[ni][bi], 0, 0, 0);
        }
    }

    // ---- fused coupling epilogue
    const int dbase = d0 + wn * 16 + koct * 4;
    #pragma unroll
    for (int bi = 0; bi < 4; bi++) {
        int b = b0 + wb * 64 + bi * 16 + ln16;
        float jp = 0.f;
        #pragma unroll
        for (int r = 0; r < 4; r++) {
            int d = dbase + r;
            if (d < HALFF) {
                float s  = acc[0][bi][r] + bias[d];
                float tt = acc[1][bi][r] + bias[d + HALFF];
                float x  = Vcur[(long)permRow[d] * BN + b];
                float ls = 0.636f * atanf(s);
                jp += ls;
                Vdst[(long)d * BN + b] = expf(ls) * x + tt;
            }
        }
        jp += __shfl_xor(jp, 16);
        jp += __shfl_xor(jp, 32);
        if (koct == 0)
            atomicAdd(&jac[b], jp);
    }
}

// ---------------------------------------------------------------------------
// transposes + jac helpers
// ---------------------------------------------------------------------------
__global__ void tin_k(const float* __restrict__ x, float* __restrict__ V)
{
    __shared__ float tile[32][33];
    int tx = threadIdx.x, ty = threadIdx.y;
    int d0 = blockIdx.x * 32, b0 = blockIdx.y * 32;
    #pragma unroll
    for (int j = 0; j < 4; j++) {
        int d = d0 + tx, b = b0 + ty + j * 8;
        tile[ty + j * 8][tx] = (d < DF) ? x[(long)b * DF + d] : 0.f;
    }
    __syncthreads();
    #pragma unroll
    for (int j = 0; j < 4; j++) {
        int d = d0 + ty + j * 8, b = b0 + tx;
        if (d < DF) V[(long)d * BN + b] = tile[tx][ty + j * 8];
    }
}

__global__ void tout_k(const float* __restrict__ V, float* __restrict__ z)
{
    __shared__ float tile[32][33];
    int tx = threadIdx.x, ty = threadIdx.y;
    int d0 = blockIdx.x * 32, b0 = blockIdx.y * 32;
    #pragma unroll
    for (int j = 0; j < 4; j++) {
        int d = d0 + ty + j * 8, b = b0 + tx;
        tile[ty + j * 8][tx] = (d < DF) ? V[(long)d * BN + b] : 0.f;
    }
    __syncthreads();
    #pragma unroll
    for (int j = 0; j < 4; j++) {
        int b = b0 + ty + j * 8, d = d0 + tx;
        if (d < DF) z[(long)b * DF + d] = tile[tx][ty + j * 8];
    }
}

__global__ void zero_k(float* __restrict__ p)
{
    p[blockIdx.x * 256 + threadIdx.x] = 0.f;
}

__global__ void cjac_k(const float* __restrict__ jac, float* __restrict__ out)
{
    int i = blockIdx.x * 256 + threadIdx.x;
    out[i] = jac[i];
}

// ---------------------------------------------------------------------------
extern "C" void kernel_launch(void* const* d_in, const int* in_sizes, int n_in,
                              void* d_out, int out_size, void* d_ws, size_t ws_size,
                              hipStream_t stream)
{
    const float* x     = (const float*)d_in[0];
    const int*   l     = (const int*)d_in[1];
    const int*   perms = (const int*)d_in[2];
    const float* s1W1  = (const float*)d_in[3];
    const float* s1b1  = (const float*)d_in[4];
    const float* s1W2  = (const float*)d_in[5];
    const float* s1b2  = (const float*)d_in[6];
    const float* s2W1  = (const float*)d_in[7];
    const float* s2b1  = (const float*)d_in[8];
    const float* s2W2  = (const float*)d_in[9];
    const float* s2b2  = (const float*)d_in[10];
    float* out = (float*)d_out;

    char* ws = (char*)d_ws;
    const size_t VB = (size_t)DF * BN * 4;            // 12,845,056
    float* Va   = (float*)ws;
    float* Vb   = (float*)(ws + VB);
    f16*   Hbuf = (f16*)  (ws + 2 * VB);              // 4 MB
    float* jac  = (float*)(ws + 2 * VB + (size_t)BN * HIDF * 2);
    char*  wb   = ws + 2 * VB + (size_t)BN * HIDF * 2 + 65536;

    const long W1E = (long)HIDF * KS1;                // halves per W1 matrix
    const long W2E = (long)DF * KS2;                  // halves per W2 matrix
    f16* Wf1_s2 = (f16*)wb;
    f16* Wf1_s1 = Wf1_s2 + W1E * NBLK;
    f16* Wf2_s2 = Wf1_s1 + W1E * NBLK;
    f16* Wf2_s1 = Wf2_s2 + W2E * NBLK;

    dim3 pb(32, 8);
    prep_k<<<dim3((KS1 / 32) * 16, NBLK), pb, 0, stream>>>(s2W1, Wf1_s2, HALFF, HIDF, KS1, 402L * 512, W1E);
    prep_k<<<dim3((KS1 / 32) * 16, NBLK), pb, 0, stream>>>(s1W1, Wf1_s1, HALFF, HIDF, KS1, 402L * 512, W1E);
    prep_k<<<dim3((KS2 / 32) * 25, NBLK), pb, 0, stream>>>(s2W2, Wf2_s2, HIDF, DF, KS2, 512L * 784, W2E);
    prep_k<<<dim3((KS2 / 32) * 25, NBLK), pb, 0, stream>>>(s1W2, Wf2_s1, HIDF, DF, KS2, 512L * 784, W2E);

    tin_k<<<dim3(25, 128), dim3(32, 8), 0, stream>>>(x, Va);
    zero_k<<<16, 256, 0, stream>>>(jac);

    float* Vc = Va;
    float* Vn = Vb;
    for (int i = 0; i < NBLK; i++) {
        const int* perm = perms + (long)i * DF;
        // substep 2: r2 = f2([x2, c]);  y1 = exp(ls2)*x1 + t2
        gemm1_k<<<dim3(8, 32), 256, 0, stream>>>(Vc, perm + HALFF,
                Wf1_s2 + i * W1E, s2W1 + (long)i * 402 * 512 + (long)HALFF * HIDF,
                s2b1 + (long)i * 512, l, Hbuf);
        gemm2c_k<<<dim3(13, 32), 256, 0, stream>>>(Hbuf, Wf2_s2 + i * W2E,
                s2b2 + (long)i * 784, Vc, perm, Vn, jac);
        // substep 1: r1 = f1([y1, c]);  y2 = exp(ls1)*x2 + t1
        gemm1_k<<<dim3(8, 32), 256, 0, stream>>>(Vn, nullptr,
                Wf1_s1 + i * W1E, s1W1 + (long)i * 402 * 512 + (long)HALFF * HIDF,
                s1b1 + (long)i * 512, l, Hbuf);
        gemm2c_k<<<dim3(13, 32), 256, 0, stream>>>(Hbuf, Wf2_s1 + i * W2E,
                s1b2 + (long)i * 784, Vc, perm + HALFF, Vn + (long)HALFF * BN, jac);
        float* tmp = Vc; Vc = Vn; Vn = tmp;
    }

    tout_k<<<dim3(25, 128), dim3(32, 8), 0, stream>>>(Vc, out);
    cjac_k<<<16, 256, 0, stream>>>(jac, out + (long)BN * DF);
}

// Round 4
// 2010.272 us; speedup vs baseline: 1.8476x; 1.8476x over previous
//
#include <hip/hip_runtime.h>

#define BN 4096     // batch
#define DF 784
#define HALFF 392
#define HIDF 512
#define NBLK 20
#define KS1 448     // padded K for GEMM1 (392 -> 7*64)
#define KS2 512     // K for GEMM2 (8*64)
#define PP  848     // P pitch (halves): 784 rounded up, 16B-aligned rows
#define YP  448     // Y1/Y2 pitch (halves)

typedef _Float16 f16;
typedef _Float16 half4v __attribute__((ext_vector_type(4)));
typedef _Float16 half8v __attribute__((ext_vector_type(8)));
typedef float    fx4    __attribute__((ext_vector_type(4)));

// ---------------------------------------------------------------------------
// prep_k: convert fp32 weights [m][k][N] (k-major) -> fp16 [m][n][KS] (n-major),
// zero-padding k in [K, KS). Classic 32x32 LDS transpose.
// grid ((KS/32) * ceil(N/32), M), block (32, 8).
// ---------------------------------------------------------------------------
__global__ void prep_k(const float* __restrict__ src, f16* __restrict__ dst,
                       int K, int N, int KS, long srcMat, long dstMat)
{
    __shared__ float tile[32][33];
    const int m = blockIdx.y;
    const int ktiles = KS >> 5;
    const int kt = blockIdx.x % ktiles, nt = blockIdx.x / ktiles;
    const int tx = threadIdx.x, ty = threadIdx.y;
    const float* s = src + (long)m * srcMat;
    f16* d = dst + (long)m * dstMat;
    #pragma unroll
    for (int j = 0; j < 4; j++) {
        int k = kt * 32 + ty + j * 8, n = nt * 32 + tx;
        tile[ty + j * 8][tx] = (k < K && n < N) ? s[(long)k * N + n] : 0.f;
    }
    __syncthreads();
    #pragma unroll
    for (int j = 0; j < 4; j++) {
        int n = nt * 32 + ty + j * 8, k = kt * 32 + tx;
        if (n < N) d[(long)n * KS + k] = (f16)tile[tx][ty + j * 8];
    }
}

// ---------------------------------------------------------------------------
// GEMM1: Hb[b][n] = relu( sum_k Wf[n][k]*A[b][k] + Wcond[l[b]][n] + bias[n] )
// A: fp16 [b][k] contiguous (pitch apitch halves); pad k-range multiplies
// zero weights. Wf: fp16 [512][KS1]. Hb: fp16 [4096][512].
// A staged via swizzled b128 copy; W fragments direct from global (L2-hot).
// grid (8, 32), block 256.
// ---------------------------------------------------------------------------
__global__ __launch_bounds__(256)
void gemm1_k(const f16* __restrict__ A, long apitch,
             const f16* __restrict__ Wf, const float* __restrict__ Wcond,
             const float* __restrict__ bias, const int* __restrict__ lvec,
             f16* __restrict__ Hb)
{
    __shared__ __align__(16) f16 Al[128 * 64];   // [b][chunk^(b&7)][8]

    const int tid  = threadIdx.x;
    const int n0   = blockIdx.x * 64;
    const int b0   = blockIdx.y * 128;
    const int wid  = tid >> 6, lane = tid & 63;
    const int wn   = wid >> 1, wb = wid & 1;
    const int ln16 = lane & 15, koct = lane >> 4;

    const int br = tid & 127;        // LDS row (b) this thread stages
    const int cb = (tid >> 7) * 4;   // chunk base (0 or 4)

    fx4 acc[2][4];
    #pragma unroll
    for (int i = 0; i < 2; i++)
        #pragma unroll
        for (int j = 0; j < 4; j++) acc[i][j] = (fx4)0.f;

    for (int k0 = 0; k0 < KS1; k0 += 64) {
        __syncthreads();
        // ---- stage A tile: pure fp16 swizzled copy (b128 in, b128 out)
        #pragma unroll
        for (int ch = 0; ch < 4; ch++) {
            int c = cb + ch;
            half8v h = *(const half8v*)&A[(long)(b0 + br) * apitch + k0 + c * 8];
            *(half8v*)&Al[br * 64 + ((c ^ (br & 7)) * 8)] = h;
        }
        __syncthreads();
        // ---- fragments + MFMA (2 k-slices of 32)
        #pragma unroll
        for (int ks = 0; ks < 2; ks++) {
            half8v af[2], bf[4];
            #pragma unroll
            for (int ni = 0; ni < 2; ni++) {
                int n = n0 + wn * 32 + ni * 16 + ln16;
                af[ni] = *(const half8v*)&Wf[(long)n * KS1 + k0 + ks * 32 + koct * 8];
            }
            #pragma unroll
            for (int bi = 0; bi < 4; bi++) {
                int b = wb * 64 + bi * 16 + ln16;
                int c = (ks * 4 + koct) ^ (b & 7);
                bf[bi] = *(const half8v*)&Al[b * 64 + c * 8];
            }
            #pragma unroll
            for (int ni = 0; ni < 2; ni++)
                #pragma unroll
                for (int bi = 0; bi < 4; bi++)
                    acc[ni][bi] = __builtin_amdgcn_mfma_f32_16x16x32_f16(af[ni], bf[bi], acc[ni][bi], 0, 0, 0);
        }
    }

    // ---- epilogue: + bias + cond row, relu, store Hb[b][n]
    #pragma unroll
    for (int bi = 0; bi < 4; bi++) {
        int b = b0 + wb * 64 + bi * 16 + ln16;
        int lvb = lvec[b];
        const float* crow = Wcond + (long)lvb * HIDF;
        #pragma unroll
        for (int ni = 0; ni < 2; ni++) {
            int nb = n0 + wn * 32 + ni * 16 + koct * 4;
            half4v o;
            #pragma unroll
            for (int r = 0; r < 4; r++) {
                float v = acc[ni][bi][r] + bias[nb + r] + crow[nb + r];
                o[r] = (f16)fmaxf(v, 0.f);
            }
            *(half4v*)&Hb[(long)b * HIDF + nb] = o;
        }
    }
}

// ---------------------------------------------------------------------------
// Fused GEMM2 + coupling.
//   s[d][b] = sum_k Wf[d][k]     * Hb[b][k] + bias[d]
//   t[d][b] = sum_k Wf[d+392][k] * Hb[b][k] + bias[d+392]
//   ls = 0.636*atan(s); Y[b][d] = (f16)(exp(ls)*Px[b][d] + t); jac[b] += ls
// Px: fp16 x-source (already offset; pitch PP). Y: fp16 [b][d] pitch YP.
// grid (13, 32), block 256.
// ---------------------------------------------------------------------------
__global__ __launch_bounds__(256)
void gemm2c_k(const f16* __restrict__ Hb, const f16* __restrict__ Wf,
              const float* __restrict__ bias, const f16* __restrict__ Px,
              f16* __restrict__ Y, float* __restrict__ jac)
{
    __shared__ __align__(16) f16 Bl[128 * 64];

    const int tid  = threadIdx.x;
    const int d0   = blockIdx.x * 32;
    const int b0   = blockIdx.y * 128;
    const int wid  = tid >> 6, lane = tid & 63;
    const int wn   = wid >> 1, wb = wid & 1;
    const int ln16 = lane & 15, koct = lane >> 4;

    const int br = tid & 127;
    const int cb = (tid >> 7) * 4;

    fx4 acc[2][4];
    #pragma unroll
    for (int i = 0; i < 2; i++)
        #pragma unroll
        for (int j = 0; j < 4; j++) acc[i][j] = (fx4)0.f;

    const int dr  = d0 + wn * 16 + ln16;
    const int drc = (dr < HALFF) ? dr : (HALFF - 1);

    for (int k0 = 0; k0 < HIDF; k0 += 64) {
        __syncthreads();
        #pragma unroll
        for (int ch = 0; ch < 4; ch++) {
            int c = cb + ch;
            half8v h = *(const half8v*)&Hb[(long)(b0 + br) * HIDF + k0 + c * 8];
            *(half8v*)&Bl[br * 64 + ((c ^ (br & 7)) * 8)] = h;
        }
        __syncthreads();
        #pragma unroll
        for (int ks = 0; ks < 2; ks++) {
            half8v af[2], bf[4];
            af[0] = *(const half8v*)&Wf[(long)drc * KS2 + k0 + ks * 32 + koct * 8];
            af[1] = *(const half8v*)&Wf[(long)(drc + HALFF) * KS2 + k0 + ks * 32 + koct * 8];
            #pragma unroll
            for (int bi = 0; bi < 4; bi++) {
                int b = wb * 64 + bi * 16 + ln16;
                int c = (ks * 4 + koct) ^ (b & 7);
                bf[bi] = *(const half8v*)&Bl[b * 64 + c * 8];
            }
            #pragma unroll
            for (int ni = 0; ni < 2; ni++)
                #pragma unroll
                for (int bi = 0; bi < 4; bi++)
                    acc[ni][bi] = __builtin_amdgcn_mfma_f32_16x16x32_f16(af[ni], bf[bi], acc[ni][bi], 0, 0, 0);
        }
    }

    // ---- fused coupling epilogue (quad-aligned: 392 % 4 == 0)
    const int dbase = d0 + wn * 16 + koct * 4;
    #pragma unroll
    for (int bi = 0; bi < 4; bi++) {
        int b = b0 + wb * 64 + bi * 16 + ln16;
        float jp = 0.f;
        if (dbase < HALFF) {
            half4v xv = *(const half4v*)&Px[(long)b * PP + dbase];
            half4v o;
            #pragma unroll
            for (int r = 0; r < 4; r++) {
                float s  = acc[0][bi][r] + bias[dbase + r];
                float tt = acc[1][bi][r] + bias[dbase + r + HALFF];
                float ls = 0.636f * atanf(s);
                jp += ls;
                o[r] = (f16)(expf(ls) * (float)xv[r] + tt);
            }
            *(half4v*)&Y[(long)b * YP + dbase] = o;
        }
        jp += __shfl_xor(jp, 16);
        jp += __shfl_xor(jp, 32);
        if (koct == 0)
            atomicAdd(&jac[b], jp);
    }
}

// ---------------------------------------------------------------------------
// pm_k: P[b][dpos] = (perm[dpos] < 392) ? Y1[b][perm] : Y2[b][perm-392]
// Row-local gather (perm loads are wave-uniform -> s_load; Y rows L2-hot),
// coalesced half8 write. grid (98, 16), block 256.
// ---------------------------------------------------------------------------
__global__ __launch_bounds__(256)
void pm_k(const f16* __restrict__ Y1, const f16* __restrict__ Y2,
          const int* __restrict__ perm, f16* __restrict__ P)
{
    const int dp = blockIdx.x * 8;
    const int b  = blockIdx.y * 256 + threadIdx.x;
    half8v o;
    #pragma unroll
    for (int j = 0; j < 8; j++) {
        int r = perm[dp + j];
        o[j] = (r < HALFF) ? Y1[(long)b * YP + r] : Y2[(long)b * YP + r - HALFF];
    }
    *(half8v*)&P[(long)b * PP + dp] = o;
}

// tin_pm: P0[b][dpos] = (f16) x[b][perm0[dpos]].  grid (98,16), block 256.
__global__ __launch_bounds__(256)
void tin_pm_k(const float* __restrict__ x, const int* __restrict__ perm,
              f16* __restrict__ P)
{
    const int dp = blockIdx.x * 8;
    const int b  = blockIdx.y * 256 + threadIdx.x;
    half8v o;
    #pragma unroll
    for (int j = 0; j < 8; j++) {
        int r = perm[dp + j];
        o[j] = (f16)x[(long)b * DF + r];
    }
    *(half8v*)&P[(long)b * PP + dp] = o;
}

// fin_k: out[b][d] = fp32(concat(Y1,Y2)[b][d]).  grid 4096, block 256 (196 act).
__global__ __launch_bounds__(256)
void fin_k(const f16* __restrict__ Y1, const f16* __restrict__ Y2,
           float* __restrict__ out)
{
    const int b = blockIdx.x;
    const int d = threadIdx.x * 4;
    if (d < DF) {
        const f16* src = (d < HALFF) ? &Y1[(long)b * YP + d]
                                     : &Y2[(long)b * YP + d - HALFF];
        half4v v = *(const half4v*)src;
        fx4 o;
        #pragma unroll
        for (int r = 0; r < 4; r++) o[r] = (float)v[r];
        *(fx4*)&out[(long)b * DF + d] = o;
    }
}

__global__ void zero_k(float* __restrict__ p)
{
    p[blockIdx.x * 256 + threadIdx.x] = 0.f;
}

__global__ void cjac_k(const float* __restrict__ jac, float* __restrict__ out)
{
    int i = blockIdx.x * 256 + threadIdx.x;
    out[i] = jac[i];
}

// ---------------------------------------------------------------------------
extern "C" void kernel_launch(void* const* d_in, const int* in_sizes, int n_in,
                              void* d_out, int out_size, void* d_ws, size_t ws_size,
                              hipStream_t stream)
{
    const float* x     = (const float*)d_in[0];
    const int*   l     = (const int*)d_in[1];
    const int*   perms = (const int*)d_in[2];
    const float* s1W1  = (const float*)d_in[3];
    const float* s1b1  = (const float*)d_in[4];
    const float* s1W2  = (const float*)d_in[5];
    const float* s1b2  = (const float*)d_in[6];
    const float* s2W1  = (const float*)d_in[7];
    const float* s2b1  = (const float*)d_in[8];
    const float* s2W2  = (const float*)d_in[9];
    const float* s2b2  = (const float*)d_in[10];
    float* out = (float*)d_out;

    char* ws = (char*)d_ws;
    f16*   P    = (f16*)ws;                                   // 6.95 MB
    f16*   Y1   = (f16*)(ws + (size_t)BN * PP * 2);           // 3.67 MB
    f16*   Y2   = Y1 + (size_t)BN * YP;                       // 3.67 MB
    f16*   Hb   = Y2 + (size_t)BN * YP;                       // 4.19 MB
    float* jac  = (float*)(Hb + (size_t)BN * HIDF);           // 16 KB
    f16*   wb   = (f16*)((char*)jac + 65536);

    const long W1E = (long)HIDF * KS1;
    const long W2E = (long)DF * KS2;
    f16* Wf1_s2 = wb;
    f16* Wf1_s1 = Wf1_s2 + W1E * NBLK;
    f16* Wf2_s2 = Wf1_s1 + W1E * NBLK;
    f16* Wf2_s1 = Wf2_s2 + W2E * NBLK;

    dim3 pb(32, 8);
    prep_k<<<dim3((KS1 / 32) * 16, NBLK), pb, 0, stream>>>(s2W1, Wf1_s2, HALFF, HIDF, KS1, 402L * 512, W1E);
    prep_k<<<dim3((KS1 / 32) * 16, NBLK), pb, 0, stream>>>(s1W1, Wf1_s1, HALFF, HIDF, KS1, 402L * 512, W1E);
    prep_k<<<dim3((KS2 / 32) * 25, NBLK), pb, 0, stream>>>(s2W2, Wf2_s2, HIDF, DF, KS2, 512L * 784, W2E);
    prep_k<<<dim3((KS2 / 32) * 25, NBLK), pb, 0, stream>>>(s1W2, Wf2_s1, HIDF, DF, KS2, 512L * 784, W2E);

    tin_pm_k<<<dim3(98, 16), 256, 0, stream>>>(x, perms, P);
    zero_k<<<16, 256, 0, stream>>>(jac);

    for (int i = 0; i < NBLK; i++) {
        // substep 2: A = x2 = P[:,392:], x-mult = x1 = P[:,0:392] -> Y1
        gemm1_k<<<dim3(8, 32), 256, 0, stream>>>(P + HALFF, (long)PP,
                Wf1_s2 + i * W1E, s2W1 + (long)i * 402 * 512 + (long)HALFF * HIDF,
                s2b1 + (long)i * 512, l, Hb);
        gemm2c_k<<<dim3(13, 32), 256, 0, stream>>>(Hb, Wf2_s2 + i * W2E,
                s2b2 + (long)i * 784, P, Y1, jac);
        // substep 1: A = y1 = Y1, x-mult = x2 = P[:,392:] -> Y2
        gemm1_k<<<dim3(8, 32), 256, 0, stream>>>(Y1, (long)YP,
                Wf1_s1 + i * W1E, s1W1 + (long)i * 402 * 512 + (long)HALFF * HIDF,
                s1b1 + (long)i * 512, l, Hb);
        gemm2c_k<<<dim3(13, 32), 256, 0, stream>>>(Hb, Wf2_s1 + i * W2E,
                s1b2 + (long)i * 784, P + HALFF, Y2, jac);
        if (i < NBLK - 1)
            pm_k<<<dim3(98, 16), 256, 0, stream>>>(Y1, Y2,
                    perms + (long)(i + 1) * DF, P);
    }

    fin_k<<<4096, 256, 0, stream>>>(Y1, Y2, out);
    cjac_k<<<16, 256, 0, stream>>>(jac, out + (long)BN * DF);
}